// Round 1
// baseline (999.499 us; speedup 1.0000x reference)
//
#include <hip/hip_runtime.h>
#include <hip/hip_bf16.h>
#include <type_traits>

#define HW 16384
#define IMH 128
#define IMW 128
#define DIM 192
#define DIM2 384
#define NB 8
#define HEADS 8
#define CD 24

// ---------------------------------------------------------------------------
// GEMM over K=192: C[b][oc][p] = sum_ic W[oc][ic] * X[b][ic][p]
// block: 256 thr = 4 waves; wave handles 8 oc rows, lanes handle 4 px each
// tile: 32 oc x 256 px, ic chunked by 32 staged in LDS
// ---------------------------------------------------------------------------
template<typename OutT, bool PER_BATCH_W>
__global__ __launch_bounds__(256)
void gemm192_kernel(const float* __restrict__ Wm, const float* __restrict__ X,
                    OutT* __restrict__ C, int OC, long xbstride, long cbstride)
{
    __shared__ float lds[32 * 256];
    const int tid  = threadIdx.x;
    const int lane = tid & 63;
    const int wave = tid >> 6;
    const int octile = blockIdx.x;   // OC/32
    const int pxtile = blockIdx.y;   // 64
    const int b      = blockIdx.z;   // 8
    const int px0 = pxtile * 256;
    const int oc0 = octile * 32 + wave * 8;
    const float* Wb = Wm + (PER_BATCH_W ? (long)b * OC * DIM : 0);
    const float* Xb = X + (long)b * xbstride;

    float4 acc[8];
#pragma unroll
    for (int r = 0; r < 8; r++) acc[r] = make_float4(0.f, 0.f, 0.f, 0.f);

    for (int icc = 0; icc < DIM; icc += 32) {
        // stage X[icc..icc+32)[px0..px0+256) -> LDS (2048 float4 slots)
#pragma unroll
        for (int j = 0; j < 8; j++) {
            int l   = tid + 256 * j;
            int ic  = l >> 6;
            int px4 = l & 63;
            float4 v = *reinterpret_cast<const float4*>(
                Xb + (long)(icc + ic) * HW + px0 + px4 * 4);
            *reinterpret_cast<float4*>(&lds[ic * 256 + px4 * 4]) = v;
        }
        __syncthreads();
#pragma unroll 8
        for (int ic = 0; ic < 32; ic++) {
            float4 x4 = *reinterpret_cast<const float4*>(&lds[ic * 256 + lane * 4]);
#pragma unroll
            for (int r = 0; r < 8; r++) {
                float w = Wb[(oc0 + r) * DIM + icc + ic];   // wave-uniform -> s_load
                acc[r].x += w * x4.x;
                acc[r].y += w * x4.y;
                acc[r].z += w * x4.z;
                acc[r].w += w * x4.w;
            }
        }
        __syncthreads();
    }

#pragma unroll
    for (int r = 0; r < 8; r++) {
        long off = (long)b * cbstride + (long)(oc0 + r) * HW + px0 + lane * 4;
        if constexpr (std::is_same<OutT, float>::value) {
            *reinterpret_cast<float4*>(C + off) = acc[r];
        } else {
            __hip_bfloat16 h0 = __float2bfloat16(acc[r].x);
            __hip_bfloat16 h1 = __float2bfloat16(acc[r].y);
            __hip_bfloat16 h2 = __float2bfloat16(acc[r].z);
            __hip_bfloat16 h3 = __float2bfloat16(acc[r].w);
            ushort4 u = make_ushort4(*reinterpret_cast<unsigned short*>(&h0),
                                     *reinterpret_cast<unsigned short*>(&h1),
                                     *reinterpret_cast<unsigned short*>(&h2),
                                     *reinterpret_cast<unsigned short*>(&h3));
            *reinterpret_cast<ushort4*>(reinterpret_cast<unsigned short*>(C) + off) = u;
        }
    }
}

// ---------------------------------------------------------------------------
// depthwise 3x3, pad=1, in bf16 -> out f32
// ---------------------------------------------------------------------------
__global__ __launch_bounds__(256)
void dwconv_kernel(const __hip_bfloat16* __restrict__ in, const float* __restrict__ w2,
                   float* __restrict__ out)
{
    long gid = (long)blockIdx.x * 256 + threadIdx.x;  // < 8*384*16384
    int x  = (int)(gid & 127);
    int y  = (int)((gid >> 7) & 127);
    long bc = gid >> 14;           // b*384 + gc
    int gc = (int)(bc % DIM2);
    const __hip_bfloat16* inp = in + (bc << 14);
    float wv[9];
#pragma unroll
    for (int i = 0; i < 9; i++) wv[i] = w2[gc * 9 + i];   // wave-uniform
    float s = 0.f;
#pragma unroll
    for (int dy = 0; dy < 3; dy++) {
        int yy = y + dy - 1;
        if (yy < 0 || yy > 127) continue;
#pragma unroll
        for (int dx = 0; dx < 3; dx++) {
            int xx = x + dx - 1;
            if (xx < 0 || xx > 127) continue;
            s += wv[dy * 3 + dx] * __bfloat162float(inp[yy * 128 + xx]);
        }
    }
    out[gid] = s;
}

// ---------------------------------------------------------------------------
// per-row sum of squares over HW; row r = b*192 + c
// ---------------------------------------------------------------------------
__global__ __launch_bounds__(256)
void sumsq_kernel(const float* __restrict__ X, float* __restrict__ ss, long batch_stride)
{
    int r = blockIdx.x;          // 0..1535
    int b = r / DIM, c = r % DIM;
    const float* row = X + (long)b * batch_stride + (long)c * HW;
    int tid = threadIdx.x;
    float s = 0.f;
    for (int i = tid * 4; i < HW; i += 1024) {
        float4 v = *reinterpret_cast<const float4*>(row + i);
        s += v.x * v.x + v.y * v.y + v.z * v.z + v.w * v.w;
    }
    for (int o = 32; o; o >>= 1) s += __shfl_xor(s, o);
    __shared__ float lds[4];
    if ((tid & 63) == 0) lds[tid >> 6] = s;
    __syncthreads();
    if (tid == 0) ss[r] = lds[0] + lds[1] + lds[2] + lds[3];
}

// ---------------------------------------------------------------------------
// raw QK logits: block = (b, h, c); 24 dot products of length 16384
// ---------------------------------------------------------------------------
__global__ __launch_bounds__(256)
void qk_kernel(const float* __restrict__ q, const float* __restrict__ kv2,
               float* __restrict__ logits)
{
    int blk = blockIdx.x;               // b*192 + h*24 + c
    int b = blk / DIM;
    int hc = blk % DIM;
    int h = hc / CD;
    const float* qrow  = q   + ((long)b * DIM + hc) * HW;
    const float* khead = kv2 + ((long)b * DIM2 + h * CD) * HW;
    int tid = threadIdx.x;
    float acc[24];
#pragma unroll
    for (int d = 0; d < 24; d++) acc[d] = 0.f;
    for (int i = tid * 4; i < HW; i += 1024) {
        float4 q4 = *reinterpret_cast<const float4*>(qrow + i);
#pragma unroll
        for (int d = 0; d < 24; d++) {
            float4 k4 = *reinterpret_cast<const float4*>(khead + (long)d * HW + i);
            acc[d] += q4.x * k4.x + q4.y * k4.y + q4.z * k4.z + q4.w * k4.w;
        }
    }
    __shared__ float lds[4][24];
#pragma unroll
    for (int d = 0; d < 24; d++) {
        float s = acc[d];
        for (int o = 32; o; o >>= 1) s += __shfl_xor(s, o);
        if ((tid & 63) == 0) lds[tid >> 6][d] = s;
    }
    __syncthreads();
    if (tid < 24)
        logits[(long)blk * 24 + tid] = lds[0][tid] + lds[1][tid] + lds[2][tid] + lds[3][tid];
}

// ---------------------------------------------------------------------------
// normalize + scale + softmax over d (24)
// ---------------------------------------------------------------------------
__global__ __launch_bounds__(64)
void softmax_kernel(const float* __restrict__ logits, const float* __restrict__ qss,
                    const float* __restrict__ kss, const float* __restrict__ scale,
                    float* __restrict__ prob)
{
    int blk = blockIdx.x;   // b*192 + h*24 + c
    int b = blk / DIM;
    int hc = blk % DIM;
    int h = hc / CD;
    int d = threadIdx.x;    // 0..63
    float val = -1e30f;
    if (d < 24) {
        float qn = fmaxf(sqrtf(qss[blk]), 1e-12f);
        float kn = fmaxf(sqrtf(kss[b * DIM + h * CD + d]), 1e-12f);
        val = logits[(long)blk * 24 + d] * scale[h] / (qn * kn);
    }
    float m = val;
    for (int o = 32; o; o >>= 1) m = fmaxf(m, __shfl_xor(m, o));
    float e = (d < 24) ? expf(val - m) : 0.f;
    float s = e;
    for (int o = 32; o; o >>= 1) s += __shfl_xor(s, o);
    if (d < 24) prob[(long)blk * 24 + d] = e / s;
}

// ---------------------------------------------------------------------------
// M[b][oc][gvc] = sum_c P[oc][h*24+c] * prob[b,h,c,d]   (gvc = h*24+d)
// ---------------------------------------------------------------------------
__global__ __launch_bounds__(256)
void buildm_kernel(const float* __restrict__ Pw, const float* __restrict__ prob,
                   float* __restrict__ M)
{
    long flat = (long)blockIdx.x * 256 + threadIdx.x;
    if (flat >= (long)NB * DIM * DIM) return;
    int b   = (int)(flat / (DIM * DIM));
    int rem = (int)(flat % (DIM * DIM));
    int oc  = rem / DIM;
    int gvc = rem % DIM;
    int h = gvc / CD, d = gvc % CD;
    float s = 0.f;
#pragma unroll
    for (int c = 0; c < CD; c++)
        s += Pw[oc * DIM + h * CD + c] * prob[(((long)b * HEADS + h) * CD + c) * CD + d];
    M[flat] = s;
}

// ---------------------------------------------------------------------------
extern "C" void kernel_launch(void* const* d_in, const int* in_sizes, int n_in,
                              void* d_out, int out_size, void* d_ws, size_t ws_size,
                              hipStream_t stream)
{
    const float* kv    = (const float*)d_in[0];
    const float* q     = (const float*)d_in[1];
    const float* w1    = (const float*)d_in[2];   // (384,192,1,1)
    const float* w2    = (const float*)d_in[3];   // (384,1,3,3)
    const float* pw    = (const float*)d_in[4];   // (192,192,1,1)
    const float* scale = (const float*)d_in[5];   // (8,1,1)
    float* out = (float*)d_out;

    char* ws = (char*)d_ws;
    const long KVF1_BYTES = (long)NB * DIM2 * HW * 2;  // bf16, 96 MiB
    const long KV2_BYTES  = (long)NB * DIM2 * HW * 4;  // f32, 192 MiB
    __hip_bfloat16* kvf1 = (__hip_bfloat16*)ws;
    float* kv2    = (float*)(ws + KVF1_BYTES);
    float* qss    = (float*)(ws + KVF1_BYTES + KV2_BYTES);
    float* kss    = qss + NB * DIM;
    float* logits = kss + NB * DIM;
    float* prob   = logits + (long)NB * HEADS * CD * CD;
    float* M      = prob + (long)NB * HEADS * CD * CD;

    // 1) 1x1 conv dim->2*dim (GEMM, bf16 out)
    dim3 g1(DIM2 / 32, 64, NB);
    gemm192_kernel<__hip_bfloat16, false><<<g1, 256, 0, stream>>>(
        w1, kv, kvf1, DIM2, (long)DIM * HW, (long)DIM2 * HW);

    // 2) depthwise 3x3 -> kv2 (f32): [b][384][hw]; k = ch 0..191, v = 192..383
    dwconv_kernel<<<(NB * DIM2 * HW) / 256, 256, 0, stream>>>(kvf1, w2, kv2);

    // 3) sum-of-squares for q and k rows
    sumsq_kernel<<<NB * DIM, 256, 0, stream>>>(q,   qss, (long)DIM * HW);
    sumsq_kernel<<<NB * DIM, 256, 0, stream>>>(kv2, kss, (long)DIM2 * HW);

    // 4) raw QK dot products
    qk_kernel<<<NB * DIM, 256, 0, stream>>>(q, kv2, logits);

    // 5) normalize + scale + softmax
    softmax_kernel<<<NB * DIM, 64, 0, stream>>>(logits, qss, kss, scale, prob);

    // 6) fold proj into attention: M[b] = proj_w @ blockdiag(attn[b])
    buildm_kernel<<<(NB * DIM * DIM + 255) / 256, 256, 0, stream>>>(pw, prob, M);

    // 7) out = M[b] @ v  (exact fusion of PV + 1x1 proj)
    dim3 g2(DIM / 32, 64, NB);
    gemm192_kernel<float, true><<<g2, 256, 0, stream>>>(
        M, kv2 + (long)DIM * HW, out, DIM, (long)DIM2 * HW, (long)DIM * HW);
}

// Round 2
// 359.437 us; speedup vs baseline: 2.7807x; 2.7807x over previous
//
#include <hip/hip_runtime.h>
#include <hip/hip_bf16.h>

#define HW 16384
#define DIM 192
#define DIM2 384
#define NB 8
#define HEADS 8
#define CD 24

typedef float f32x4 __attribute__((ext_vector_type(4)));
typedef short bf16x8 __attribute__((ext_vector_type(8)));

__device__ __forceinline__ short f2bf(float f) {
    __hip_bfloat16 h = __float2bfloat16(f);
    return *reinterpret_cast<short*>(&h);
}
__device__ __forceinline__ float bf2f(short s) {
    __hip_bfloat16 h = *reinterpret_cast<__hip_bfloat16*>(&s);
    return __bfloat162float(h);
}

// ---------------------------------------------------------------------------
// MFMA GEMM: C[b][oc][px] = sum_ic A[oc][ic] * B[b][ic][px], K = 192.
// Tile: MT oc x 128 px. 4 waves as 2(oc) x 2(px); wave = MT/2 oc x 64 px.
// A staged fully in LDS (stride 200 shorts), B in 32-k double-buffered chunks
// (stride 40 shorts). Fragments read as single ds_read_b128 (16B-aligned).
// ---------------------------------------------------------------------------
template<int MT, bool A_F32, bool B_F32, bool PER_BATCH_A, bool OUT_F32>
__global__ __launch_bounds__(256, 2)
void gemm_mfma(const void* __restrict__ Ag, const void* __restrict__ Bg,
               void* __restrict__ Cg, long bstrideA, long bstrideB, long bstrideC)
{
    constexpr int MFRAG = MT / 32;
    __shared__ short lds_a[MT * 200];
    __shared__ short lds_b[2][128 * 40];

    const int tid  = threadIdx.x;
    const int lane = tid & 63;
    const int wave = tid >> 6;
    const int wm = wave >> 1, wn = wave & 1;
    const int oc0 = blockIdx.x * MT;
    const int px0 = blockIdx.y * 128;
    const int b   = blockIdx.z;

    // ---- stage A (MT x 192) once ----
    if constexpr (A_F32) {
        const float* Af = (const float*)Ag + (PER_BATCH_A ? (long)b * bstrideA : 0);
        for (int idx = tid; idx < MT * 48; idx += 256) {
            int oc = idx / 48, icq = (idx % 48) * 4;
            float4 v = *reinterpret_cast<const float4*>(Af + (long)(oc0 + oc) * DIM + icq);
            *reinterpret_cast<short4*>(&lds_a[oc * 200 + icq]) =
                make_short4(f2bf(v.x), f2bf(v.y), f2bf(v.z), f2bf(v.w));
        }
    } else {
        const short* Ah = (const short*)Ag + (PER_BATCH_A ? (long)b * bstrideA : 0);
        for (int idx = tid; idx < MT * 48; idx += 256) {
            int oc = idx / 48, icq = (idx % 48) * 4;
            *reinterpret_cast<short4*>(&lds_a[oc * 200 + icq]) =
                *reinterpret_cast<const short4*>(Ah + (long)(oc0 + oc) * DIM + icq);
        }
    }

    // ---- B chunk staging (transpose to [px][k] layout) ----
    auto stageB = [&](int chunk, int buf) {
        const int p4  = tid & 31;       // px quad
        const int icq = tid >> 5;       // 0..7 -> 4 ic each
        const int kc  = chunk * 32 + icq * 4;
        const int pxl = p4 * 4;
        short* dst = &lds_b[buf][0];
        if constexpr (B_F32) {
            const float* Bf = (const float*)Bg + (long)b * bstrideB + (long)kc * HW + px0 + pxl;
            float4 v0 = *(const float4*)(Bf);
            float4 v1 = *(const float4*)(Bf + HW);
            float4 v2 = *(const float4*)(Bf + 2 * HW);
            float4 v3 = *(const float4*)(Bf + 3 * HW);
            *(short4*)&dst[(pxl + 0) * 40 + icq * 4] = make_short4(f2bf(v0.x), f2bf(v1.x), f2bf(v2.x), f2bf(v3.x));
            *(short4*)&dst[(pxl + 1) * 40 + icq * 4] = make_short4(f2bf(v0.y), f2bf(v1.y), f2bf(v2.y), f2bf(v3.y));
            *(short4*)&dst[(pxl + 2) * 40 + icq * 4] = make_short4(f2bf(v0.z), f2bf(v1.z), f2bf(v2.z), f2bf(v3.z));
            *(short4*)&dst[(pxl + 3) * 40 + icq * 4] = make_short4(f2bf(v0.w), f2bf(v1.w), f2bf(v2.w), f2bf(v3.w));
        } else {
            const short* Bh = (const short*)Bg + (long)b * bstrideB + (long)kc * HW + px0 + pxl;
            short4 v0 = *(const short4*)(Bh);
            short4 v1 = *(const short4*)(Bh + HW);
            short4 v2 = *(const short4*)(Bh + 2 * HW);
            short4 v3 = *(const short4*)(Bh + 3 * HW);
            *(short4*)&dst[(pxl + 0) * 40 + icq * 4] = make_short4(v0.x, v1.x, v2.x, v3.x);
            *(short4*)&dst[(pxl + 1) * 40 + icq * 4] = make_short4(v0.y, v1.y, v2.y, v3.y);
            *(short4*)&dst[(pxl + 2) * 40 + icq * 4] = make_short4(v0.z, v1.z, v2.z, v3.z);
            *(short4*)&dst[(pxl + 3) * 40 + icq * 4] = make_short4(v0.w, v1.w, v2.w, v3.w);
        }
    };

    f32x4 acc[MFRAG][4];
#pragma unroll
    for (int m = 0; m < MFRAG; m++)
#pragma unroll
        for (int n = 0; n < 4; n++) acc[m][n] = (f32x4){0.f, 0.f, 0.f, 0.f};

    stageB(0, 0);
    __syncthreads();

#pragma unroll
    for (int c = 0; c < 6; c++) {
        const int buf = c & 1;
        if (c < 5) stageB(c + 1, buf ^ 1);
        bf16x8 a[MFRAG], bv[4];
        const int arow = wm * (MT / 2) + (lane & 15);
        const int ko   = c * 32 + (lane >> 4) * 8;
#pragma unroll
        for (int m = 0; m < MFRAG; m++)
            a[m] = *reinterpret_cast<const bf16x8*>(&lds_a[(arow + m * 16) * 200 + ko]);
        const int brow = wn * 64 + (lane & 15);
        const int kl   = (lane >> 4) * 8;
#pragma unroll
        for (int n = 0; n < 4; n++)
            bv[n] = *reinterpret_cast<const bf16x8*>(&lds_b[buf][(brow + n * 16) * 40 + kl]);
#pragma unroll
        for (int m = 0; m < MFRAG; m++)
#pragma unroll
            for (int n = 0; n < 4; n++)
                acc[m][n] = __builtin_amdgcn_mfma_f32_16x16x32_bf16(a[m], bv[n], acc[m][n], 0, 0, 0);
        __syncthreads();
    }

    const int ocb = oc0 + wm * (MT / 2) + (lane >> 4) * 4;
    const int pxb = px0 + wn * 64 + (lane & 15);
#pragma unroll
    for (int m = 0; m < MFRAG; m++)
#pragma unroll
        for (int n = 0; n < 4; n++)
#pragma unroll
            for (int r = 0; r < 4; r++) {
                long off = (long)b * bstrideC + (long)(ocb + m * 16 + r) * HW + (pxb + n * 16);
                if constexpr (OUT_F32) ((float*)Cg)[off] = acc[m][n][r];
                else                   ((short*)Cg)[off] = f2bf(acc[m][n][r]);
            }
}

// ---------------------------------------------------------------------------
// depthwise 3x3 (pad 1) on one 128x128 image per block; bf16 in -> bf16 out,
// fused sum-of-squares for k channels (gc < 192).
// ---------------------------------------------------------------------------
__global__ __launch_bounds__(256)
void dwconv_sumsq(const short* __restrict__ in, const float* __restrict__ w2,
                  short* __restrict__ outp, float* __restrict__ kss)
{
    __shared__ short img[16384];
    __shared__ float red[4];
    const long bgc = blockIdx.x;           // b*384 + gc
    const int  gc  = (int)(bgc % DIM2);
    const int  b   = (int)(bgc / DIM2);
    const int  tid = threadIdx.x;
    const short* src = in + (bgc << 14);
#pragma unroll
    for (int j = 0; j < 16; j++) {
        int idx = (tid + j * 256) * 4;
        *reinterpret_cast<short4*>(&img[idx]) = *reinterpret_cast<const short4*>(&src[idx]);
    }
    float wv[9];
#pragma unroll
    for (int i = 0; i < 9; i++) wv[i] = w2[gc * 9 + i];
    __syncthreads();

    short* dst = outp + (bgc << 14);
    float ssq = 0.f;
    for (int j = 0; j < 64; j++) {
        int px = tid + j * 256;
        int y = px >> 7, x = px & 127;
        float s = 0.f;
#pragma unroll
        for (int dy = 0; dy < 3; dy++) {
            int yy = y + dy - 1;
            if ((unsigned)yy > 127u) continue;
#pragma unroll
            for (int dx = 0; dx < 3; dx++) {
                int xx = x + dx - 1;
                if ((unsigned)xx > 127u) continue;
                s += wv[dy * 3 + dx] * bf2f(img[yy * 128 + xx]);
            }
        }
        dst[px] = f2bf(s);
        ssq += s * s;
    }
    for (int o = 32; o; o >>= 1) ssq += __shfl_xor(ssq, o);
    if ((tid & 63) == 0) red[tid >> 6] = ssq;
    __syncthreads();
    if (gc < DIM && tid == 0)
        kss[b * DIM + gc] = red[0] + red[1] + red[2] + red[3];
}

// ---------------------------------------------------------------------------
// q: f32 -> bf16 + per-row sum of squares
// ---------------------------------------------------------------------------
__global__ __launch_bounds__(256)
void qcvt_sumsq(const float* __restrict__ q, short* __restrict__ qb, float* __restrict__ qss)
{
    __shared__ float red[4];
    const int row = blockIdx.x;            // b*192 + c
    const int tid = threadIdx.x;
    const float* src = q + (long)row * HW;
    short* dst = qb + (long)row * HW;
    float ssq = 0.f;
#pragma unroll
    for (int j = 0; j < 16; j++) {
        int i = (tid + j * 256) * 4;
        float4 v = *reinterpret_cast<const float4*>(src + i);
        ssq += v.x * v.x + v.y * v.y + v.z * v.z + v.w * v.w;
        *reinterpret_cast<short4*>(dst + i) =
            make_short4(f2bf(v.x), f2bf(v.y), f2bf(v.z), f2bf(v.w));
    }
    for (int o = 32; o; o >>= 1) ssq += __shfl_xor(ssq, o);
    if ((tid & 63) == 0) red[tid >> 6] = ssq;
    __syncthreads();
    if (tid == 0) qss[row] = red[0] + red[1] + red[2] + red[3];
}

// ---------------------------------------------------------------------------
// raw QK^T partials: grid (bh=64, ksplit=8); each block: 24x24 over 2048 px.
// lane = (cb,db) 8x8, 3x3 register block; waves split px by 64.
// ---------------------------------------------------------------------------
__global__ __launch_bounds__(256)
void qk_partial(const short* __restrict__ qb, const short* __restrict__ kvb,
                float* __restrict__ part)
{
    constexpr int QST = 264;               // padded row stride (shorts)
    __shared__ short qs[24 * QST];
    __shared__ short ks_[24 * QST];
    __shared__ float red[4][576];
    const int bh  = blockIdx.x;            // b*8 + h
    const int ksp = blockIdx.y;            // 0..7
    const int b = bh >> 3, h = bh & 7;
    const short* qh = qb  + ((long)b * DIM  + h * CD) * HW + ksp * 2048;
    const short* kh = kvb + ((long)b * DIM2 + h * CD) * HW + ksp * 2048;
    const int tid = threadIdx.x, lane = tid & 63, w = tid >> 6;
    const int cb = lane >> 3, db = lane & 7;

    float acc[3][3] = {{0.f,0.f,0.f},{0.f,0.f,0.f},{0.f,0.f,0.f}};
    for (int sc = 0; sc < 8; sc++) {
        for (int idx = tid; idx < 24 * 64; idx += 256) {
            int r = idx >> 6, p4 = (idx & 63) * 4;
            *reinterpret_cast<short4*>(&qs[r * QST + p4]) =
                *reinterpret_cast<const short4*>(&qh[(long)r * HW + sc * 256 + p4]);
            *reinterpret_cast<short4*>(&ks_[r * QST + p4]) =
                *reinterpret_cast<const short4*>(&kh[(long)r * HW + sc * 256 + p4]);
        }
        __syncthreads();
        const int pxb = w * 64;
#pragma unroll
        for (int pp = 0; pp < 8; pp++) {
            bf16x8 qv[3], kvv[3];
#pragma unroll
            for (int i = 0; i < 3; i++)
                qv[i] = *reinterpret_cast<const bf16x8*>(&qs[(cb * 3 + i) * QST + pxb + pp * 8]);
#pragma unroll
            for (int i = 0; i < 3; i++)
                kvv[i] = *reinterpret_cast<const bf16x8*>(&ks_[(db * 3 + i) * QST + pxb + pp * 8]);
#pragma unroll
            for (int i = 0; i < 3; i++) {
                float qf[8];
#pragma unroll
                for (int e = 0; e < 8; e++) qf[e] = bf2f(qv[i][e]);
#pragma unroll
                for (int jj = 0; jj < 3; jj++)
#pragma unroll
                    for (int e = 0; e < 8; e++)
                        acc[i][jj] += qf[e] * bf2f(kvv[jj][e]);
            }
        }
        __syncthreads();
    }
#pragma unroll
    for (int i = 0; i < 3; i++)
#pragma unroll
        for (int jj = 0; jj < 3; jj++)
            red[w][(cb * 3 + i) * 24 + db * 3 + jj] = acc[i][jj];
    __syncthreads();
    float* dst = part + ((long)bh * 8 + ksp) * 576;
    for (int e = tid; e < 576; e += 256)
        dst[e] = red[0][e] + red[1][e] + red[2][e] + red[3][e];
}

// ---------------------------------------------------------------------------
// reduce split-K partials, normalize, scale, softmax over d (24)
// ---------------------------------------------------------------------------
__global__ __launch_bounds__(64)
void softmax_kernel(const float* __restrict__ part, const float* __restrict__ qss,
                    const float* __restrict__ kss, const float* __restrict__ scale,
                    float* __restrict__ prob)
{
    const int blk = blockIdx.x;            // b*192 + h*24 + c
    const int b = blk / DIM;
    const int hc = blk % DIM;
    const int h = hc / CD, c = hc % CD;
    const int d = threadIdx.x;
    float val = -1e30f;
    if (d < CD) {
        const float* p0 = part + ((long)(b * 8 + h) * 8) * 576 + c * CD + d;
        float raw = 0.f;
#pragma unroll
        for (int ks = 0; ks < 8; ks++) raw += p0[ks * 576];
        float qn = fmaxf(sqrtf(qss[blk]), 1e-12f);
        float kn = fmaxf(sqrtf(kss[b * DIM + h * CD + d]), 1e-12f);
        val = raw * scale[h] / (qn * kn);
    }
    float m = val;
    for (int o = 32; o; o >>= 1) m = fmaxf(m, __shfl_xor(m, o));
    float e = (d < CD) ? expf(val - m) : 0.f;
    float s = e;
    for (int o = 32; o; o >>= 1) s += __shfl_xor(s, o);
    if (d < CD) prob[(long)blk * CD + d] = e / s;
}

// ---------------------------------------------------------------------------
// M[b][oc][gvc] = sum_c pw[oc][h*24+c] * prob[b,h,c,d]   (gvc = h*24+d), bf16
// ---------------------------------------------------------------------------
__global__ __launch_bounds__(256)
void buildm(const float* __restrict__ pw, const float* __restrict__ prob,
            short* __restrict__ M)
{
    long flat = (long)blockIdx.x * 256 + threadIdx.x;
    if (flat >= (long)NB * DIM * DIM) return;
    int bb  = (int)(flat / (DIM * DIM));
    int rem = (int)(flat % (DIM * DIM));
    int oc = rem / DIM, gvc = rem % DIM;
    int h = gvc / CD, d = gvc % CD;
    float s = 0.f;
#pragma unroll
    for (int c = 0; c < CD; c++)
        s += pw[oc * DIM + h * CD + c] * prob[((long)bb * 8 + h) * 576 + c * CD + d];
    M[flat] = f2bf(s);
}

// ---------------------------------------------------------------------------
extern "C" void kernel_launch(void* const* d_in, const int* in_sizes, int n_in,
                              void* d_out, int out_size, void* d_ws, size_t ws_size,
                              hipStream_t stream)
{
    const float* kv    = (const float*)d_in[0];
    const float* q     = (const float*)d_in[1];
    const float* w1    = (const float*)d_in[2];   // (384,192)
    const float* w2    = (const float*)d_in[3];   // (384,9)
    const float* pw    = (const float*)d_in[4];   // (192,192)
    const float* scale = (const float*)d_in[5];   // (8)
    float* out = (float*)d_out;

    char* ws = (char*)d_ws;
    const long SZ_KVF1 = (long)NB * DIM2 * HW * 2;   // 96 MiB bf16
    const long SZ_KVB  = (long)NB * DIM2 * HW * 2;   // 96 MiB bf16
    const long SZ_QB   = (long)NB * DIM  * HW * 2;   // 48 MiB bf16
    short* kvf1 = (short*)ws;
    short* kvb  = (short*)(ws + SZ_KVF1);
    short* qb   = (short*)(ws + SZ_KVF1 + SZ_KVB);
    float* qss  = (float*)(ws + SZ_KVF1 + SZ_KVB + SZ_QB);
    float* kss  = qss + NB * DIM;
    float* part = kss + NB * DIM;                    // 64*8*576 f32
    float* prob = part + (long)64 * 8 * 576;         // 64*576 f32
    short* M    = (short*)(prob + (long)64 * 576);   // 8*192*192 bf16

    // 1) 1x1 conv (GEMM) kv -> kvf1 (bf16)
    gemm_mfma<128, true, true, false, false><<<dim3(3, 128, NB), 256, 0, stream>>>(
        w1, kv, kvf1, 0, (long)DIM * HW, (long)DIM2 * HW);

    // 2) depthwise 3x3 + k sumsq -> kvb (bf16), kss
    dwconv_sumsq<<<NB * DIM2, 256, 0, stream>>>(kvf1, w2, kvb, kss);

    // 3) q -> bf16 + sumsq
    qcvt_sumsq<<<NB * DIM, 256, 0, stream>>>(q, qb, qss);

    // 4) QK^T split-K partials
    qk_partial<<<dim3(64, 8), 256, 0, stream>>>(qb, kvb, part);

    // 5) softmax
    softmax_kernel<<<NB * DIM, 64, 0, stream>>>(part, qss, kss, scale, prob);

    // 6) fold proj into attention (bf16 M)
    buildm<<<(int)(((long)NB * DIM * DIM + 255) / 256), 256, 0, stream>>>(pw, prob, M);

    // 7) out = M[b] @ v  (PV + proj fused), f32 out
    gemm_mfma<96, false, false, true, true><<<dim3(2, 128, NB), 256, 0, stream>>>(
        M, kvb + (long)DIM * HW, out, (long)DIM * DIM, (long)DIM2 * HW, (long)DIM * HW);
}

// Round 3
// 290.406 us; speedup vs baseline: 3.4417x; 1.2377x over previous
//
#include <hip/hip_runtime.h>
#include <hip/hip_bf16.h>

#define HW 16384
#define DIM 192
#define DIM2 384
#define NB 8
#define HEADS 8
#define CD 24

typedef float f32x4 __attribute__((ext_vector_type(4)));
typedef short bf16x8 __attribute__((ext_vector_type(8)));

__device__ __forceinline__ short f2bf(float f) {
    __hip_bfloat16 h = __float2bfloat16(f);
    return *reinterpret_cast<short*>(&h);
}
__device__ __forceinline__ float bf2f(short s) {
    __hip_bfloat16 h = *reinterpret_cast<__hip_bfloat16*>(&s);
    return __bfloat162float(h);
}

// ---------------------------------------------------------------------------
// prep: w1 (384x192 f32) -> bf16
// ---------------------------------------------------------------------------
__global__ __launch_bounds__(256)
void prep_w1(const float* __restrict__ w1, short* __restrict__ wb1)
{
    int i = (blockIdx.x * 256 + threadIdx.x) * 4;
    float4 v = *reinterpret_cast<const float4*>(w1 + i);
    *reinterpret_cast<short4*>(wb1 + i) =
        make_short4(f2bf(v.x), f2bf(v.y), f2bf(v.z), f2bf(v.w));
}

// ---------------------------------------------------------------------------
// MFMA GEMM, K=192: C[b][oc][px] = sum_ic A[oc][ic] * B[b][ic][px].
// Block: 128-px slab, ALL oc. B staged ONCE in LDS transposed [px][k],
// stride 200 shorts (400B = 4 mod 32 dwords -> b128 slots spread (px+j)%8:
// conflict-free writes AND reads). A (bf16) read from global (L1/L2-hot).
// One barrier total; compute loop is barrier-free.
// ---------------------------------------------------------------------------
template<int NOCT, bool B_F32, bool PER_BATCH_A, bool OUT_F32>
__global__ __launch_bounds__(256, 3)
void gemm_k192(const short* __restrict__ Ab, const void* __restrict__ Bg,
               void* __restrict__ Cg, long bstrideB, long bstrideC)
{
    __shared__ short ldsb[128 * 200];
    const int tid  = threadIdx.x;
    const int lane = tid & 63;
    const int wave = tid >> 6;
    const int px0  = blockIdx.x * 128;
    const int b    = blockIdx.y;

    // ---- stage B-slab [128 px][192 k] ----
    {
        const int px = tid & 127;
        const int kh = tid >> 7;               // k-half: 0 or 1 (96 rows each)
        short* dst = &ldsb[px * 200 + kh * 96];
        if constexpr (B_F32) {
            const float* src = (const float*)Bg + (long)b * bstrideB
                             + (long)kh * 96 * HW + px0 + px;
#pragma unroll
            for (int g = 0; g < 12; g++) {
                bf16x8 s;
#pragma unroll
                for (int e = 0; e < 8; e++)
                    s[e] = f2bf(src[(long)(g * 8 + e) * HW]);
                *reinterpret_cast<bf16x8*>(&dst[g * 8]) = s;
            }
        } else {
            const unsigned short* src = (const unsigned short*)Bg + (long)b * bstrideB
                                      + (long)kh * 96 * HW + px0 + px;
#pragma unroll
            for (int g = 0; g < 12; g++) {
                bf16x8 s;
#pragma unroll
                for (int e = 0; e < 8; e++)
                    s[e] = (short)src[(long)(g * 8 + e) * HW];
                *reinterpret_cast<bf16x8*>(&dst[g * 8]) = s;
            }
        }
    }
    __syncthreads();

    const int row = lane & 15;
    const int kg  = (lane >> 4) * 8;
    const short* A0 = Ab + (PER_BATCH_A ? (long)b * NOCT * 16 * DIM : 0);

    for (int mp = 0; mp < NOCT / 2; mp++) {
        const int oc0 = mp * 32;
        bf16x8 a[2][6];
#pragma unroll
        for (int m = 0; m < 2; m++)
#pragma unroll
            for (int c = 0; c < 6; c++)
                a[m][c] = *reinterpret_cast<const bf16x8*>(
                    &A0[(long)(oc0 + m * 16 + row) * DIM + c * 32 + kg]);

        f32x4 acc[2][2];
#pragma unroll
        for (int m = 0; m < 2; m++)
#pragma unroll
            for (int n = 0; n < 2; n++) acc[m][n] = (f32x4){0.f, 0.f, 0.f, 0.f};

#pragma unroll
        for (int c = 0; c < 6; c++) {
            bf16x8 bv[2];
#pragma unroll
            for (int n = 0; n < 2; n++)
                bv[n] = *reinterpret_cast<const bf16x8*>(
                    &ldsb[(wave * 32 + n * 16 + row) * 200 + c * 32 + kg]);
#pragma unroll
            for (int m = 0; m < 2; m++)
#pragma unroll
                for (int n = 0; n < 2; n++)
                    acc[m][n] = __builtin_amdgcn_mfma_f32_16x16x32_bf16(
                        a[m][c], bv[n], acc[m][n], 0, 0, 0);
        }

        const int ocb = oc0 + (lane >> 4) * 4;
        const int pxb = px0 + wave * 32 + row;
#pragma unroll
        for (int m = 0; m < 2; m++)
#pragma unroll
            for (int n = 0; n < 2; n++)
#pragma unroll
                for (int r = 0; r < 4; r++) {
                    long off = (long)b * bstrideC + (long)(ocb + m * 16 + r) * HW
                             + pxb + n * 16;
                    if constexpr (OUT_F32) ((float*)Cg)[off] = acc[m][n][r];
                    else                   ((short*)Cg)[off] = f2bf(acc[m][n][r]);
                }
    }
}

// ---------------------------------------------------------------------------
// depthwise 3x3 (pad 1), one 128x128 image per block; bf16 in/out,
// fused sum-of-squares for k channels (gc < 192).
// ---------------------------------------------------------------------------
__global__ __launch_bounds__(256)
void dwconv_sumsq(const short* __restrict__ in, const float* __restrict__ w2,
                  short* __restrict__ outp, float* __restrict__ kss)
{
    __shared__ short img[16384];
    __shared__ float red[4];
    const long bgc = blockIdx.x;           // b*384 + gc
    const int  gc  = (int)(bgc % DIM2);
    const int  b   = (int)(bgc / DIM2);
    const int  tid = threadIdx.x;
    const short* src = in + (bgc << 14);
#pragma unroll
    for (int j = 0; j < 16; j++) {
        int idx = (tid + j * 256) * 4;
        *reinterpret_cast<short4*>(&img[idx]) = *reinterpret_cast<const short4*>(&src[idx]);
    }
    float wv[9];
#pragma unroll
    for (int i = 0; i < 9; i++) wv[i] = w2[gc * 9 + i];
    __syncthreads();

    short* dst = outp + (bgc << 14);
    float ssq = 0.f;
    for (int j = 0; j < 64; j++) {
        int px = tid + j * 256;
        int y = px >> 7, x = px & 127;
        float s = 0.f;
#pragma unroll
        for (int dy = 0; dy < 3; dy++) {
            int yy = y + dy - 1;
            if ((unsigned)yy > 127u) continue;
#pragma unroll
            for (int dx = 0; dx < 3; dx++) {
                int xx = x + dx - 1;
                if ((unsigned)xx > 127u) continue;
                s += wv[dy * 3 + dx] * bf2f(img[yy * 128 + xx]);
            }
        }
        dst[px] = f2bf(s);
        ssq += s * s;
    }
    for (int o = 32; o; o >>= 1) ssq += __shfl_xor(ssq, o);
    if ((tid & 63) == 0) red[tid >> 6] = ssq;
    __syncthreads();
    if (gc < DIM && tid == 0)
        kss[b * DIM + gc] = red[0] + red[1] + red[2] + red[3];
}

// ---------------------------------------------------------------------------
// QK^T via MFMA over contiguous px (the contraction dim!). Zero LDS, zero
// transpose: A-frag = Q[c][px] (f32->bf16 in reg), B-frag = K[d][px] (bf16).
// Grid (32 px-splits, 64 bh); 1 wave computes 32x32 over 512 px.
// Fused q sum-of-squares (f32) -> per-split partials.
// ---------------------------------------------------------------------------
__global__ __launch_bounds__(64)
void qk_mfma(const float* __restrict__ q, const short* __restrict__ kvb,
             float* __restrict__ part, float* __restrict__ pssq)
{
    const int split = blockIdx.x;          // 0..31
    const int bh    = blockIdx.y;          // b*8 + h
    const int b = bh >> 3, h = bh & 7;
    const int lane = threadIdx.x;
    const int row = lane & 15;
    const int kg  = (lane >> 4) * 8;

    const int qr1 = min(h * CD + 16 + row, DIM - 1);   // clamp (h=7 tail OOB)
    const float* q0 = q + ((long)b * DIM + h * CD + row) * HW + split * 512 + kg;
    const float* q1 = q + ((long)b * DIM + qr1) * HW + split * 512 + kg;
    const short* k0 = kvb + ((long)b * DIM2 + h * CD + row) * HW + split * 512 + kg;
    const short* k1 = k0 + (long)16 * HW;

    f32x4 acc[2][2];
#pragma unroll
    for (int m = 0; m < 2; m++)
#pragma unroll
        for (int n = 0; n < 2; n++) acc[m][n] = (f32x4){0.f, 0.f, 0.f, 0.f};
    float ssq0 = 0.f, ssq1 = 0.f;

#pragma unroll 4
    for (int s = 0; s < 16; s++) {
        const int px = s * 32;
        float4 qa = *reinterpret_cast<const float4*>(q0 + px);
        float4 qb = *reinterpret_cast<const float4*>(q0 + px + 4);
        float4 qc = *reinterpret_cast<const float4*>(q1 + px);
        float4 qd = *reinterpret_cast<const float4*>(q1 + px + 4);
        bf16x8 b0 = *reinterpret_cast<const bf16x8*>(k0 + px);
        bf16x8 b1 = *reinterpret_cast<const bf16x8*>(k1 + px);
        ssq0 += qa.x*qa.x + qa.y*qa.y + qa.z*qa.z + qa.w*qa.w
              + qb.x*qb.x + qb.y*qb.y + qb.z*qb.z + qb.w*qb.w;
        ssq1 += qc.x*qc.x + qc.y*qc.y + qc.z*qc.z + qc.w*qc.w
              + qd.x*qd.x + qd.y*qd.y + qd.z*qd.z + qd.w*qd.w;
        bf16x8 a0, a1;
        a0[0]=f2bf(qa.x); a0[1]=f2bf(qa.y); a0[2]=f2bf(qa.z); a0[3]=f2bf(qa.w);
        a0[4]=f2bf(qb.x); a0[5]=f2bf(qb.y); a0[6]=f2bf(qb.z); a0[7]=f2bf(qb.w);
        a1[0]=f2bf(qc.x); a1[1]=f2bf(qc.y); a1[2]=f2bf(qc.z); a1[3]=f2bf(qc.w);
        a1[4]=f2bf(qd.x); a1[5]=f2bf(qd.y); a1[6]=f2bf(qd.z); a1[7]=f2bf(qd.w);
        acc[0][0] = __builtin_amdgcn_mfma_f32_16x16x32_bf16(a0, b0, acc[0][0], 0, 0, 0);
        acc[0][1] = __builtin_amdgcn_mfma_f32_16x16x32_bf16(a0, b1, acc[0][1], 0, 0, 0);
        acc[1][0] = __builtin_amdgcn_mfma_f32_16x16x32_bf16(a1, b0, acc[1][0], 0, 0, 0);
        acc[1][1] = __builtin_amdgcn_mfma_f32_16x16x32_bf16(a1, b1, acc[1][1], 0, 0, 0);
    }

    // reduce ssq across the 4 lane-groups sharing a row (xor 16, 32)
    ssq0 += __shfl_xor(ssq0, 16); ssq0 += __shfl_xor(ssq0, 32);
    ssq1 += __shfl_xor(ssq1, 16); ssq1 += __shfl_xor(ssq1, 32);

    float* pd = part + ((long)split * 64 + bh) * 576;
#pragma unroll
    for (int m = 0; m < 2; m++)
#pragma unroll
        for (int n = 0; n < 2; n++)
#pragma unroll
            for (int r = 0; r < 4; r++) {
                int c = m * 16 + (lane >> 4) * 4 + r;
                int d = n * 16 + row;
                if (c < CD && d < CD) pd[c * CD + d] = acc[m][n][r];
            }
    if (lane < 16) {
        float* ps = pssq + ((long)split * 64 + bh) * 32;
        ps[lane]      = ssq0;
        ps[16 + lane] = ssq1;
    }
}

// ---------------------------------------------------------------------------
// reduce split partials, normalize, scale, softmax over d (24)
// ---------------------------------------------------------------------------
__global__ __launch_bounds__(64)
void softmax_kernel(const float* __restrict__ part, const float* __restrict__ pssq,
                    const float* __restrict__ kss, const float* __restrict__ scale,
                    float* __restrict__ prob)
{
    const int blk = blockIdx.x;            // b*192 + h*24 + c
    const int b = blk / DIM;
    const int hc = blk % DIM;
    const int h = hc / CD, c = hc % CD;
    const int bh = b * 8 + h;
    const int d = threadIdx.x;

    float qs = 0.f;
    for (int s = 0; s < 32; s++) qs += pssq[((long)s * 64 + bh) * 32 + c];

    float val = -1e30f;
    if (d < CD) {
        float raw = 0.f;
        for (int s = 0; s < 32; s++) raw += part[((long)s * 64 + bh) * 576 + c * CD + d];
        float qn = fmaxf(sqrtf(qs), 1e-12f);
        float kn = fmaxf(sqrtf(kss[b * DIM + h * CD + d]), 1e-12f);
        val = raw * scale[h] / (qn * kn);
    }
    float m = val;
    for (int o = 32; o; o >>= 1) m = fmaxf(m, __shfl_xor(m, o));
    float e = (d < CD) ? expf(val - m) : 0.f;
    float s = e;
    for (int o = 32; o; o >>= 1) s += __shfl_xor(s, o);
    if (d < CD) prob[(long)blk * CD + d] = e / s;
}

// ---------------------------------------------------------------------------
// M[b][oc][gvc] = sum_c pw[oc][h*24+c] * prob[b,h,c,d]   (gvc=h*24+d), bf16
// ---------------------------------------------------------------------------
__global__ __launch_bounds__(256)
void buildm(const float* __restrict__ pw, const float* __restrict__ prob,
            short* __restrict__ M)
{
    long flat = (long)blockIdx.x * 256 + threadIdx.x;
    if (flat >= (long)NB * DIM * DIM) return;
    int bb  = (int)(flat / (DIM * DIM));
    int rem = (int)(flat % (DIM * DIM));
    int oc = rem / DIM, gvc = rem % DIM;
    int h = gvc / CD, d = gvc % CD;
    float s = 0.f;
#pragma unroll
    for (int c = 0; c < CD; c++)
        s += pw[oc * DIM + h * CD + c] * prob[((long)bb * DIM + h * CD + c) * CD + d];
    M[flat] = f2bf(s);
}

// ---------------------------------------------------------------------------
extern "C" void kernel_launch(void* const* d_in, const int* in_sizes, int n_in,
                              void* d_out, int out_size, void* d_ws, size_t ws_size,
                              hipStream_t stream)
{
    const float* kv    = (const float*)d_in[0];
    const float* q     = (const float*)d_in[1];
    const float* w1    = (const float*)d_in[2];   // (384,192)
    const float* w2    = (const float*)d_in[3];   // (384,9)
    const float* pw    = (const float*)d_in[4];   // (192,192)
    const float* scale = (const float*)d_in[5];   // (8)
    float* out = (float*)d_out;

    char* ws = (char*)d_ws;
    long off = 0;
    auto alloc = [&](long bytes) { char* p = ws + off; off += (bytes + 255) & ~255L; return p; };
    short* kvf1 = (short*)alloc((long)NB * DIM2 * HW * 2);   // 96 MiB
    short* kvb  = (short*)alloc((long)NB * DIM2 * HW * 2);   // 96 MiB
    short* wb1  = (short*)alloc((long)DIM2 * DIM * 2);
    float* kss  = (float*)alloc((long)NB * DIM * 4);
    float* part = (float*)alloc((long)32 * 64 * 576 * 4);
    float* pssq = (float*)alloc((long)32 * 64 * 32 * 4);
    float* prob = (float*)alloc((long)64 * 576 * 4);
    short* M    = (short*)alloc((long)NB * DIM * DIM * 2);

    // 1) w1 -> bf16
    prep_w1<<<DIM2 * DIM / 1024, 256, 0, stream>>>(w1, wb1);

    // 2) 1x1 conv (GEMM): kvf1 = w1 @ kv, bf16 out
    gemm_k192<24, true, false, false><<<dim3(128, NB), 256, 0, stream>>>(
        wb1, kv, kvf1, (long)DIM * HW, (long)DIM2 * HW);

    // 3) depthwise 3x3 + k sumsq
    dwconv_sumsq<<<NB * DIM2, 256, 0, stream>>>(kvf1, w2, kvb, kss);

    // 4) QK^T partials + q sumsq partials (MFMA over px)
    qk_mfma<<<dim3(32, 64), 64, 0, stream>>>(q, kvb, part, pssq);

    // 5) softmax
    softmax_kernel<<<NB * DIM, 64, 0, stream>>>(part, pssq, kss, scale, prob);

    // 6) fold proj into attention: M[b] = pw @ blockdiag(attn[b]), bf16
    buildm<<<(int)(((long)NB * DIM * DIM + 255) / 256), 256, 0, stream>>>(pw, prob, M);

    // 7) out = M[b] @ v  (PV + proj fused), f32 out
    gemm_k192<12, false, true, true><<<dim3(128, NB), 256, 0, stream>>>(
        M, kvb + (long)DIM * HW, out, (long)DIM2 * HW, (long)DIM * HW);
}